// Round 4
// baseline (1126.989 us; speedup 1.0000x reference)
//
#include <hip/hip_runtime.h>

#define NN   50000
#define NE   262144
#define NOCP 32768
#define EAVA (NE - NOCP)   // 229376 = 7 * 32768
#define NG   64
#define HD   128
#define CAP  48
#define CHNK 32768

typedef _Float16 f16x8 __attribute__((ext_vector_type(8)));
typedef _Float16 f16x2 __attribute__((ext_vector_type(2)));
typedef float f32x4 __attribute__((ext_vector_type(4)));

__device__ __forceinline__ float elu_f(float v) { return v > 0.f ? v : (expf(v) - 1.f); }

__device__ __forceinline__ unsigned fenc(float f) {
  unsigned u = __float_as_uint(f);
  return (u & 0x80000000u) ? ~u : (u | 0x80000000u);
}
__device__ __forceinline__ float fdec(unsigned u) {
  return __uint_as_float((u & 0x80000000u) ? (u & 0x7fffffffu) : ~u);
}

// async global->LDS 16B per lane; LDS dst = wave-uniform base (+ lane*16 implicit)
__device__ __forceinline__ void dma16(const void* g, void* l) {
  __builtin_amdgcn_global_load_lds((const __attribute__((address_space(1))) unsigned int*)g,
                                   (__attribute__((address_space(3))) unsigned int*)l,
                                   16, 0, 0);
}

__global__ __launch_bounds__(256) void zero_i(int* __restrict__ p, int n) {
  for (int i = blockIdx.x * 256 + threadIdx.x; i < n; i += gridDim.x * 256) p[i] = 0;
}

__global__ void init_small(unsigned* mx_enc, float* denom, unsigned* pmax_enc, int* amin) {
  int t = threadIdx.x;
  if (t < NG) { mx_enc[t] = 0u; denom[t] = 0.f; pmax_enc[t] = 0u; amin[t] = EAVA; }
}

// ---------------- GNN aggregation (bucket-then-gather) ----------------
__global__ __launch_bounds__(256) void bucket_kernel(const int* __restrict__ ei,
    int* __restrict__ cnt, int* __restrict__ bucket) {
  int e = blockIdx.x * 256 + threadIdx.x;
  if (e >= NE) return;
  int dst = ei[NE + e];
  int slot = atomicAdd(&cnt[dst], 1);
  if (slot < CAP) bucket[(size_t)dst * CAP + slot] = e;
}

// gather: fp32 sums, emit hi/lo fp16 xs rows directly
__global__ __launch_bounds__(256) void gather_kernel(const float* __restrict__ x,
    const int* __restrict__ ei, const int* __restrict__ cnt, const int* __restrict__ bucket,
    _Float16* __restrict__ xah, _Float16* __restrict__ xal,
    _Float16* __restrict__ xoh, _Float16* __restrict__ xol) {
  int n = blockIdx.x * 4 + (threadIdx.x >> 6);
  if (n >= NN) return;
  int lane = threadIdx.x & 63;
  int c = cnt[n];
  if (c > CAP) c = CAP;
  float2 aall = make_float2(0.f, 0.f), aocp = aall;
  const int* bk = bucket + (size_t)n * CAP;
  for (int i = 0; i < c; ++i) {
    int e = bk[i];
    int src = ei[e];
    float2 v = *(const float2*)(x + (size_t)src * HD + lane * 2);
    aall.x += v.x; aall.y += v.y;
    if (e < NOCP) { aocp.x += v.x; aocp.y += v.y; }
  }
  _Float16 h0 = (_Float16)aall.x, h1 = (_Float16)aall.y;
  _Float16 g0 = (_Float16)aocp.x, g1 = (_Float16)aocp.y;
  f16x2 vh = {h0, h1};
  f16x2 vl = {(_Float16)(aall.x - (float)h0), (_Float16)(aall.y - (float)h1)};
  f16x2 wh = {g0, g1};
  f16x2 wl = {(_Float16)(aocp.x - (float)g0), (_Float16)(aocp.y - (float)g1)};
  size_t off = (size_t)n * HD + lane * 2;
  *(f16x2*)(xah + off) = vh;
  *(f16x2*)(xal + off) = vl;
  *(f16x2*)(xoh + off) = wh;
  *(f16x2*)(xol + off) = wl;
}

// fp32 array -> hi/lo fp16 (8 elems/thread)
__global__ __launch_bounds__(256) void split_f32(const float* __restrict__ r,
    _Float16* __restrict__ rh, _Float16* __restrict__ rl, int n8) {
  int t = blockIdx.x * 256 + threadIdx.x;
  if (t >= n8) return;
  const float4* p = (const float4*)(r + (size_t)t * 8);
  float4 v0 = p[0], v1 = p[1];
  float vv[8] = {v0.x, v0.y, v0.z, v0.w, v1.x, v1.y, v1.z, v1.w};
  f16x8 hv, lv;
#pragma unroll
  for (int j = 0; j < 8; ++j) {
    _Float16 hh = (_Float16)vv[j];
    hv[j] = hh;
    lv[j] = (_Float16)(vv[j] - (float)hh);
  }
  *(f16x8*)(rh + (size_t)t * 8) = hv;
  *(f16x8*)(rl + (size_t)t * 8) = lv;
}

// W34 = Wr3 @ Wp1 ; b34 = br3 @ Wp1 + bp1
__global__ void w34_kernel(const float* __restrict__ Wr3, const float* __restrict__ Wp1,
    const float* __restrict__ br3, const float* __restrict__ bp1,
    float* __restrict__ W34, float* __restrict__ b34) {
  int i = blockIdx.x, j = threadIdx.x;  // grid 256 x block 128
  float s = 0.f;
  for (int k = 0; k < 128; ++k) s += Wr3[i * 128 + k] * Wp1[k * 128 + j];
  W34[i * 128 + j] = s;
  if (i == 0) {
    float t = bp1[j];
    for (int k = 0; k < 128; ++k) t += br3[k] * Wp1[k * 128 + j];
    b34[j] = t;
  }
}

// pack W (KxN fp32 row-major) into MFMA B-fragment order, hi/lo fp16.
// chunk = kt*(N/16)+ns; lane L holds B[kt*32+(L>>4)*8+j][ns*16+(L&15)]
__global__ void pack_w(const float* __restrict__ W, int K, int N,
    _Float16* __restrict__ oh, _Float16* __restrict__ ol) {
  int chunk = blockIdx.x;
  int lane = threadIdx.x;  // 64
  int NS = N >> 4;
  int ns = chunk % NS, kt = chunk / NS;
  int n = ns * 16 + (lane & 15);
  int k0 = kt * 32 + (lane >> 4) * 8;
  f16x8 hv, lv;
#pragma unroll
  for (int j = 0; j < 8; ++j) {
    float v = W[(size_t)(k0 + j) * N + n];
    _Float16 hh = (_Float16)v;
    hv[j] = hh;
    lv[j] = (_Float16)(v - (float)hh);
  }
  *(f16x8*)(oh + (size_t)chunk * 512 + lane * 8) = hv;
  *(f16x8*)(ol + (size_t)chunk * 512 + lane * 8) = lv;
}

// pack Wcat = [Wself; Wnbr] (256x128) -> KT=8, NS=8
__global__ void pack_wcat(const float* __restrict__ Wself, const float* __restrict__ Wnbr,
    _Float16* __restrict__ oh, _Float16* __restrict__ ol) {
  int chunk = blockIdx.x;  // 64
  int lane = threadIdx.x;
  int ns = chunk & 7, kt = chunk >> 3;
  int n = ns * 16 + (lane & 15);
  int k0 = kt * 32 + (lane >> 4) * 8;
  f16x8 hv, lv;
#pragma unroll
  for (int j = 0; j < 8; ++j) {
    int r = k0 + j;
    float v = (r < 128) ? Wself[r * 128 + n] : Wnbr[(r - 128) * 128 + n];
    _Float16 hh = (_Float16)v;
    hv[j] = hh;
    lv[j] = (_Float16)(v - (float)hh);
  }
  *(f16x8*)(oh + (size_t)chunk * 512 + lane * 8) = hv;
  *(f16x8*)(ol + (size_t)chunk * 512 + lane * 8) = lv;
}

// ---------------- reps via MFMA split-fp16 ----------------
// reps[n] = elu(x@Wself + xsa@Wnbr + b) - elu(x@Wself + xso@Wnbr + b)
// K=256 (kt<4: x/Wself, kt>=4: xs/Wnbr). acc_o forked from acc_a after kt=3.
__global__ __launch_bounds__(256) void reps_mfma(
    const _Float16* __restrict__ xh, const _Float16* __restrict__ xl,
    const _Float16* __restrict__ xah, const _Float16* __restrict__ xal,
    const _Float16* __restrict__ xoh, const _Float16* __restrict__ xol,
    const _Float16* __restrict__ Wch, const _Float16* __restrict__ Wcl,
    const float* __restrict__ bias,
    _Float16* __restrict__ rh, _Float16* __restrict__ rl) {
  __shared__ char smem[67584] __attribute__((aligned(16)));
  _Float16* sAah = (_Float16*)smem;                    // 8 KB
  _Float16* sAal = (_Float16*)(smem + 8192);
  _Float16* sAoh = (_Float16*)(smem + 16384);
  _Float16* sAol = (_Float16*)(smem + 24576);
  _Float16* sBh  = (_Float16*)(smem + 32768);          // 8 KB
  _Float16* sBl  = (_Float16*)(smem + 40960);

  const int tid = threadIdx.x;
  const int w = tid >> 6, lane = tid & 63;
  const int bm = blockIdx.x * 128;
  const int mw = (w >> 1) * 4, nw = (w & 1) * 4;

  f32x4 acc_a[4][4], acc_o[4][4];
#pragma unroll
  for (int i = 0; i < 4; ++i)
#pragma unroll
    for (int j = 0; j < 4; ++j) acc_a[i][j] = (f32x4)0.f;

  for (int kt = 0; kt < 8; ++kt) {
    __syncthreads();
    const int col = (kt & 3) * 32 + (lane >> 4) * 8;
    const _Float16* srcH = (kt < 4) ? xh : xah;
    const _Float16* srcL = (kt < 4) ? xl : xal;
#pragma unroll
    for (int s = 0; s < 2; ++s) {
      int msub = w * 2 + s;
      int row = bm + msub * 16 + (lane & 15);
      if (row >= NN) row = NN - 1;
      dma16(srcH + (size_t)row * HD + col, (char*)smem + msub * 1024);
      dma16(srcL + (size_t)row * HD + col, (char*)smem + 8192 + msub * 1024);
      if (kt >= 4) {
        dma16(xoh + (size_t)row * HD + col, (char*)smem + 16384 + msub * 1024);
        dma16(xol + (size_t)row * HD + col, (char*)smem + 24576 + msub * 1024);
      }
    }
#pragma unroll
    for (int s = 0; s < 2; ++s) {
      int nsub = w * 2 + s;
      size_t chunk = (size_t)kt * 8 + nsub;
      dma16((const char*)Wch + chunk * 1024 + lane * 16, (char*)smem + 32768 + nsub * 1024);
      dma16((const char*)Wcl + chunk * 1024 + lane * 16, (char*)smem + 40960 + nsub * 1024);
    }
    __builtin_amdgcn_s_waitcnt(0);
    __syncthreads();

    f16x8 ah[4], al[4];
#pragma unroll
    for (int mi = 0; mi < 4; ++mi) {
      ah[mi] = *(const f16x8*)(sAah + (mw + mi) * 512 + lane * 8);
      al[mi] = *(const f16x8*)(sAal + (mw + mi) * 512 + lane * 8);
    }
#pragma unroll
    for (int ni = 0; ni < 4; ++ni) {
      f16x8 bh = *(const f16x8*)(sBh + (nw + ni) * 512 + lane * 8);
      f16x8 bl = *(const f16x8*)(sBl + (nw + ni) * 512 + lane * 8);
#pragma unroll
      for (int mi = 0; mi < 4; ++mi) {
        acc_a[mi][ni] = __builtin_amdgcn_mfma_f32_16x16x32_f16(ah[mi], bh, acc_a[mi][ni], 0, 0, 0);
        acc_a[mi][ni] = __builtin_amdgcn_mfma_f32_16x16x32_f16(al[mi], bh, acc_a[mi][ni], 0, 0, 0);
        acc_a[mi][ni] = __builtin_amdgcn_mfma_f32_16x16x32_f16(ah[mi], bl, acc_a[mi][ni], 0, 0, 0);
      }
    }
    if (kt == 3) {
#pragma unroll
      for (int i = 0; i < 4; ++i)
#pragma unroll
        for (int j = 0; j < 4; ++j) acc_o[i][j] = acc_a[i][j];
    }
    if (kt >= 4) {
      f16x8 oh4[4], ol4[4];
#pragma unroll
      for (int mi = 0; mi < 4; ++mi) {
        oh4[mi] = *(const f16x8*)(sAoh + (mw + mi) * 512 + lane * 8);
        ol4[mi] = *(const f16x8*)(sAol + (mw + mi) * 512 + lane * 8);
      }
#pragma unroll
      for (int ni = 0; ni < 4; ++ni) {
        f16x8 bh = *(const f16x8*)(sBh + (nw + ni) * 512 + lane * 8);
        f16x8 bl = *(const f16x8*)(sBl + (nw + ni) * 512 + lane * 8);
#pragma unroll
        for (int mi = 0; mi < 4; ++mi) {
          acc_o[mi][ni] = __builtin_amdgcn_mfma_f32_16x16x32_f16(oh4[mi], bh, acc_o[mi][ni], 0, 0, 0);
          acc_o[mi][ni] = __builtin_amdgcn_mfma_f32_16x16x32_f16(ol4[mi], bh, acc_o[mi][ni], 0, 0, 0);
          acc_o[mi][ni] = __builtin_amdgcn_mfma_f32_16x16x32_f16(oh4[mi], bl, acc_o[mi][ni], 0, 0, 0);
        }
      }
    }
  }
  __syncthreads();

  // elu-diff into LDS (128 x 132 fp32), then row-major hi/lo fp16 stores
  float* sC = (float*)smem;
#pragma unroll
  for (int ni = 0; ni < 4; ++ni) {
    int colL = (nw + ni) * 16 + (lane & 15);
    float bv = bias[colL];
#pragma unroll
    for (int mi = 0; mi < 4; ++mi) {
      int rowb = (mw + mi) * 16 + (lane >> 4) * 4;
#pragma unroll
      for (int r = 0; r < 4; ++r)
        sC[(rowb + r) * 132 + colL] =
            elu_f(acc_a[mi][ni][r] + bv) - elu_f(acc_o[mi][ni][r] + bv);
    }
  }
  __syncthreads();
  int row = tid >> 1, half = tid & 1;
  int grow = bm + row;
  if (grow < NN) {
#pragma unroll
    for (int c8 = 0; c8 < 8; ++c8) {
      int cb = half * 64 + c8 * 8;
      f16x8 hv, lv;
#pragma unroll
      for (int j = 0; j < 8; ++j) {
        float v = sC[row * 132 + cb + j];
        _Float16 hh = (_Float16)v;
        hv[j] = hh;
        lv[j] = (_Float16)(v - (float)hh);
      }
      *(f16x8*)(rh + (size_t)grow * HD + cb) = hv;
      *(f16x8*)(rl + (size_t)grow * HD + cb) = lv;
    }
  }
}

// ---------------- MFMA split-fp16 GEMM ----------------
// tile 128x128, 4 waves (2x2 of 64x64). M = multiple of 128 (exact).
// AMODE 0: A packed (chunk = rowtile*KT + kt); AMODE 1: gathered from reps rows (K=256)
// OMODE 0: pack hi/lo for next layer (KT_NEXT ktiles); OMODE 2: fused sel/seg epilogue
template <int KT, int NS_B, int AMODE, int OMODE, int KT_NEXT>
__global__ __launch_bounds__(256) void mfma_gemm(
    const _Float16* __restrict__ Ah, const _Float16* __restrict__ Al,
    const int* __restrict__ idx0, const int* __restrict__ idx1,
    const _Float16* __restrict__ Bh, const _Float16* __restrict__ Bl,
    const float* __restrict__ bias,
    _Float16* __restrict__ Oh, _Float16* __restrict__ Ol,
    const int* __restrict__ ei, const int* __restrict__ batchv, const int* __restrict__ yv,
    const float* __restrict__ Wp2, const float* __restrict__ bp2,
    float* __restrict__ sel, int* __restrict__ seg, int chunk_off) {
  constexpr int SMEMB = (OMODE == 2) ? 72704 : 34816;
  __shared__ char smem[SMEMB] __attribute__((aligned(16)));
  _Float16* sAh = (_Float16*)smem;               // 8 KB
  _Float16* sAl = (_Float16*)(smem + 8192);
  _Float16* sBh = (_Float16*)(smem + 16384);
  _Float16* sBl = (_Float16*)(smem + 24576);

  const int tid = threadIdx.x;
  const int w = tid >> 6, lane = tid & 63;
  const int bm = blockIdx.x * 128, bn = blockIdx.y * 128;
  const int mw = (w >> 1) * 4, nw = (w & 1) * 4;
  const int bmT = bm >> 4, bnS = bn >> 4;

  f32x4 acc[4][4];
#pragma unroll
  for (int i = 0; i < 4; ++i)
#pragma unroll
    for (int j = 0; j < 4; ++j) acc[i][j] = (f32x4)0.f;

  int i0a = 0, i0b = 0, i1a = 0, i1b = 0;
  if constexpr (AMODE == 1) {
    int rr0 = bm + (w * 2) * 16 + (lane & 15);
    i0a = idx0[rr0]; i0b = idx0[rr0 + 16];
    i1a = idx1[rr0]; i1b = idx1[rr0 + 16];
  }

  for (int kt = 0; kt < KT; ++kt) {
    __syncthreads();
    if constexpr (AMODE == 0) {
#pragma unroll
      for (int s = 0; s < 2; ++s) {
        int msub = w * 2 + s;
        size_t chunk = (size_t)(bmT + msub) * KT + kt;
        dma16((const char*)Ah + chunk * 1024 + lane * 16, (char*)smem + msub * 1024);
        dma16((const char*)Al + chunk * 1024 + lane * 16, (char*)smem + 8192 + msub * 1024);
      }
    } else {
      int col = (kt & 3) * 32 + (lane >> 4) * 8;
      int r0 = (kt < 4) ? i0a : i1a;
      int r1 = (kt < 4) ? i0b : i1b;
      dma16(Ah + (size_t)r0 * HD + col, (char*)smem + (w * 2) * 1024);
      dma16(Al + (size_t)r0 * HD + col, (char*)smem + 8192 + (w * 2) * 1024);
      dma16(Ah + (size_t)r1 * HD + col, (char*)smem + (w * 2 + 1) * 1024);
      dma16(Al + (size_t)r1 * HD + col, (char*)smem + 8192 + (w * 2 + 1) * 1024);
    }
#pragma unroll
    for (int s = 0; s < 2; ++s) {
      int nsub = w * 2 + s;
      size_t chunk = (size_t)kt * NS_B + bnS + nsub;
      dma16((const char*)Bh + chunk * 1024 + lane * 16, (char*)smem + 16384 + nsub * 1024);
      dma16((const char*)Bl + chunk * 1024 + lane * 16, (char*)smem + 24576 + nsub * 1024);
    }
    __builtin_amdgcn_s_waitcnt(0);
    __syncthreads();

    f16x8 ah[4], al[4];
#pragma unroll
    for (int mi = 0; mi < 4; ++mi) {
      ah[mi] = *(const f16x8*)(sAh + (mw + mi) * 512 + lane * 8);
      al[mi] = *(const f16x8*)(sAl + (mw + mi) * 512 + lane * 8);
    }
#pragma unroll
    for (int ni = 0; ni < 4; ++ni) {
      f16x8 bh = *(const f16x8*)(sBh + (nw + ni) * 512 + lane * 8);
      f16x8 bl = *(const f16x8*)(sBl + (nw + ni) * 512 + lane * 8);
#pragma unroll
      for (int mi = 0; mi < 4; ++mi) {
        acc[mi][ni] = __builtin_amdgcn_mfma_f32_16x16x32_f16(ah[mi], bh, acc[mi][ni], 0, 0, 0);
        acc[mi][ni] = __builtin_amdgcn_mfma_f32_16x16x32_f16(al[mi], bh, acc[mi][ni], 0, 0, 0);
        acc[mi][ni] = __builtin_amdgcn_mfma_f32_16x16x32_f16(ah[mi], bl, acc[mi][ni], 0, 0, 0);
      }
    }
  }
  __syncthreads();

  if constexpr (OMODE == 2) {
    // fused: h -> LDS, then sel[eg] = h . Wp2[:,c] + bp2[c], seg[eg] = g
    float* sC = (float*)smem;                    // 128 x 132
    float* sW = (float*)(smem + 67584);          // 1280 floats
#pragma unroll
    for (int ni = 0; ni < 4; ++ni) {
      int colL = (nw + ni) * 16 + (lane & 15);
      float bv = bias[colL];
#pragma unroll
      for (int mi = 0; mi < 4; ++mi) {
        int rowb = (mw + mi) * 16 + (lane >> 4) * 4;
#pragma unroll
        for (int r = 0; r < 4; ++r)
          sC[(rowb + r) * 132 + colL] = elu_f(acc[mi][ni][r] + bv);
      }
    }
    for (int i = tid; i < 1280; i += 256) sW[i] = Wp2[i];
    __syncthreads();
    for (int rr = 0; rr < 32; ++rr) {
      int row = w * 32 + rr;
      int eg = chunk_off + bm + row;
      int s = ei[NOCP + eg];
      int g = batchv[s];
      int c = yv[g];
      float a = sC[row * 132 + lane] * sW[lane * 10 + c] +
                sC[row * 132 + 64 + lane] * sW[(lane + 64) * 10 + c];
#pragma unroll
      for (int o = 32; o > 0; o >>= 1) a += __shfl_xor(a, o);
      if (lane == 0) { sel[eg] = a + bp2[c]; seg[eg] = g; }
    }
  } else {
    float* sC = (float*)smem;                    // 128 x 68 (phase-split)
    const int bnT32 = bn >> 5;
    for (int ph = 0; ph < 2; ++ph) {
      if ((w & 1) == ph) {
#pragma unroll
        for (int ni = 0; ni < 4; ++ni) {
          int colL = ni * 16 + (lane & 15);
          float bv = bias[bn + ph * 64 + colL];
#pragma unroll
          for (int mi = 0; mi < 4; ++mi) {
            int rowb = (mw + mi) * 16 + (lane >> 4) * 4;
#pragma unroll
            for (int r = 0; r < 4; ++r)
              sC[(rowb + r) * 68 + colL] = elu_f(acc[mi][ni][r] + bv);
          }
        }
      }
      __syncthreads();
#pragma unroll
      for (int c = 0; c < 4; ++c) {
        int chunkid = w * 4 + c;           // 16 chunks: 8 msubs x 2 ktiles
        int msub = chunkid >> 1, ktl = chunkid & 1;
        int m = msub * 16 + (lane & 15);
        int cb = ktl * 32 + (lane >> 4) * 8;
        f16x8 hv, lv;
#pragma unroll
        for (int j = 0; j < 8; ++j) {
          float v = sC[m * 68 + cb + j];
          _Float16 hh = (_Float16)v;
          hv[j] = hh;
          lv[j] = (_Float16)(v - (float)hh);
        }
        size_t gchunk = (size_t)(bmT + msub) * KT_NEXT + (bnT32 + ph * 2 + ktl);
        *(f16x8*)((char*)Oh + gchunk * 1024 + lane * 16) = hv;
        *(f16x8*)((char*)Ol + gchunk * 1024 + lane * 16) = lv;
      }
      __syncthreads();
    }
  }
}

// ---------------- tail: segment softmax/argmax ----------------
__global__ __launch_bounds__(256) void segmax_sel(const float* __restrict__ sel,
    const int* __restrict__ seg, unsigned* __restrict__ mx_enc) {
  __shared__ unsigned sm[NG];
  int tid = threadIdx.x;
  if (tid < NG) sm[tid] = 0u;
  __syncthreads();
  for (int i = blockIdx.x * blockDim.x + tid; i < EAVA; i += gridDim.x * blockDim.x)
    atomicMax(&sm[seg[i]], fenc(sel[i]));
  __syncthreads();
  if (tid < NG) atomicMax(&mx_enc[tid], sm[tid]);
}

__global__ __launch_bounds__(256) void exden_kernel(const float* __restrict__ sel,
    const int* __restrict__ seg, const unsigned* __restrict__ mx_enc,
    float* __restrict__ denom, float* __restrict__ out_probs) {
  __shared__ float sd[NG];
  __shared__ float smx[NG];
  int tid = threadIdx.x;
  if (tid < NG) { smx[tid] = fdec(mx_enc[tid]); sd[tid] = 0.f; }
  __syncthreads();
  for (int i = blockIdx.x * blockDim.x + tid; i < EAVA; i += gridDim.x * blockDim.x) {
    int g = seg[i];
    float ex = expf(sel[i] - smx[g]);
    out_probs[i] = ex;
    atomicAdd(&sd[g], ex);
  }
  __syncthreads();
  if (tid < NG) atomicAdd(&denom[tid], sd[tid]);
}

__global__ __launch_bounds__(256) void probpmax_kernel(const int* __restrict__ seg,
    const float* __restrict__ denom, float* __restrict__ out_probs,
    unsigned* __restrict__ pmax_enc) {
  __shared__ float sden[NG];
  __shared__ unsigned sp[NG];
  int tid = threadIdx.x;
  if (tid < NG) { sden[tid] = denom[tid]; sp[tid] = 0u; }
  __syncthreads();
  for (int i = blockIdx.x * blockDim.x + tid; i < EAVA; i += gridDim.x * blockDim.x) {
    int g = seg[i];
    float p = out_probs[i] / sden[g];
    out_probs[i] = p;
    atomicMax(&sp[g], fenc(p));
  }
  __syncthreads();
  if (tid < NG) atomicMax(&pmax_enc[tid], sp[tid]);
}

__global__ __launch_bounds__(256) void argmin_kernel(const int* __restrict__ seg,
    const float* __restrict__ out_probs, const unsigned* __restrict__ pmax_enc,
    int* __restrict__ amin) {
  __shared__ float spm[NG];
  __shared__ int sa[NG];
  int tid = threadIdx.x;
  if (tid < NG) { spm[tid] = fdec(pmax_enc[tid]); sa[tid] = EAVA; }
  __syncthreads();
  for (int i = blockIdx.x * blockDim.x + tid; i < EAVA; i += gridDim.x * blockDim.x) {
    int g = seg[i];
    if (out_probs[i] == spm[g]) atomicMin(&sa[g], i);
  }
  __syncthreads();
  if (tid < NG) atomicMin(&amin[tid], sa[tid]);
}

__global__ void finalize_kernel(const unsigned* __restrict__ pmax_enc,
    const int* __restrict__ amin, float* __restrict__ out) {
  int g = threadIdx.x;
  if (g < NG) {
    out[EAVA + g] = fdec(pmax_enc[g]);
    out[EAVA + NG + g] = (float)amin[g];
  }
}

extern "C" void kernel_launch(void* const* d_in, const int* in_sizes, int n_in,
                              void* d_out, int out_size, void* d_ws, size_t ws_size,
                              hipStream_t stream) {
  const float* x      = (const float*)d_in[0];
  const int*   ei     = (const int*)d_in[1];
  const int*   batchv = (const int*)d_in[2];
  const int*   yv     = (const int*)d_in[3];
  const float* Wself = (const float*)d_in[5];
  const float* Wnbr  = (const float*)d_in[6];
  const float* bgnn  = (const float*)d_in[7];
  const float* Wr1   = (const float*)d_in[8];
  const float* br1   = (const float*)d_in[9];
  const float* Wr2   = (const float*)d_in[10];
  const float* br2   = (const float*)d_in[11];
  const float* Wr3   = (const float*)d_in[12];
  const float* br3   = (const float*)d_in[13];
  const float* Wp1   = (const float*)d_in[14];
  const float* bp1   = (const float*)d_in[15];
  const float* Wp2   = (const float*)d_in[16];
  const float* bp2   = (const float*)d_in[17];
  float* out = (float*)d_out;

  char* wp = (char*)d_ws;
  auto alloc = [&](size_t bytes) -> char* {
    char* p = wp;
    wp += (bytes + 255) & ~(size_t)255;
    return p;
  };
  _Float16*  xh  = (_Float16*)alloc((size_t)NN * HD * 2);
  _Float16*  xl  = (_Float16*)alloc((size_t)NN * HD * 2);
  _Float16*  xah = (_Float16*)alloc((size_t)NN * HD * 2);
  _Float16*  xal = (_Float16*)alloc((size_t)NN * HD * 2);
  _Float16*  xoh = (_Float16*)alloc((size_t)NN * HD * 2);
  _Float16*  xol = (_Float16*)alloc((size_t)NN * HD * 2);
  _Float16*  reps_h = (_Float16*)alloc((size_t)NN * HD * 2);
  _Float16*  reps_l = (_Float16*)alloc((size_t)NN * HD * 2);
  int*       cnt    = (int*)alloc((size_t)NN * 4);
  int*       bucket = (int*)alloc((size_t)NN * CAP * 4);
  float*     sel    = (float*)alloc((size_t)EAVA * 4);
  int*       seg    = (int*)alloc((size_t)EAVA * 4);
  unsigned*  mx_enc   = (unsigned*)alloc(NG * 4);
  float*     denom    = (float*)alloc(NG * 4);
  unsigned*  pmax_enc = (unsigned*)alloc(NG * 4);
  int*       amin     = (int*)alloc(NG * 4);
  _Float16*  Wch  = (_Float16*)alloc((size_t)8 * 8 * 1024);
  _Float16*  Wcl  = (_Float16*)alloc((size_t)8 * 8 * 1024);
  _Float16*  Wr1h = (_Float16*)alloc((size_t)8 * 32 * 1024);
  _Float16*  Wr1l = (_Float16*)alloc((size_t)8 * 32 * 1024);
  _Float16*  Wr2h = (_Float16*)alloc((size_t)16 * 16 * 1024);
  _Float16*  Wr2l = (_Float16*)alloc((size_t)16 * 16 * 1024);
  float*     W34  = (float*)alloc((size_t)256 * 128 * 4);
  float*     b34  = (float*)alloc(128 * 4);
  _Float16*  W34h = (_Float16*)alloc((size_t)8 * 8 * 1024);
  _Float16*  W34l = (_Float16*)alloc((size_t)8 * 8 * 1024);
  _Float16*  b1h = (_Float16*)alloc((size_t)(CHNK / 16) * 16 * 1024);
  _Float16*  b1l = (_Float16*)alloc((size_t)(CHNK / 16) * 16 * 1024);
  _Float16*  b2h = (_Float16*)alloc((size_t)(CHNK / 16) * 8 * 1024);
  _Float16*  b2l = (_Float16*)alloc((size_t)(CHNK / 16) * 8 * 1024);
  (void)ws_size;

  // ---- prep ----
  zero_i<<<64, 256, 0, stream>>>(cnt, NN);
  init_small<<<1, 64, 0, stream>>>(mx_enc, denom, pmax_enc, amin);
  bucket_kernel<<<NE / 256, 256, 0, stream>>>(ei, cnt, bucket);
  split_f32<<<(NN * HD / 8 + 255) / 256, 256, 0, stream>>>(x, xh, xl, NN * HD / 8);
  gather_kernel<<<(NN + 3) / 4, 256, 0, stream>>>(x, ei, cnt, bucket, xah, xal, xoh, xol);
  w34_kernel<<<256, 128, 0, stream>>>(Wr3, Wp1, br3, bp1, W34, b34);
  pack_wcat<<<64, 64, 0, stream>>>(Wself, Wnbr, Wch, Wcl);
  pack_w<<<8 * 32, 64, 0, stream>>>(Wr1, 256, 512, Wr1h, Wr1l);
  pack_w<<<16 * 16, 64, 0, stream>>>(Wr2, 512, 256, Wr2h, Wr2l);
  pack_w<<<8 * 8, 64, 0, stream>>>(W34, 256, 128, W34h, W34l);
  reps_mfma<<<(NN + 127) / 128, 256, 0, stream>>>(xh, xl, xah, xal, xoh, xol, Wch, Wcl, bgnn,
                                                  reps_h, reps_l);

  // ---- per-edge MLP: 7 chunks of 32768, sel fused into L34 ----
  for (int c = 0; c < 7; ++c) {
    int co = c * CHNK;
    mfma_gemm<8, 32, 1, 0, 16><<<dim3(256, 4), 256, 0, stream>>>(
        reps_h, reps_l, ei + NOCP + co, ei + NE + NOCP + co, Wr1h, Wr1l, br1, b1h, b1l,
        nullptr, nullptr, nullptr, nullptr, nullptr, nullptr, nullptr, 0);
    mfma_gemm<16, 16, 0, 0, 8><<<dim3(256, 2), 256, 0, stream>>>(
        b1h, b1l, nullptr, nullptr, Wr2h, Wr2l, br2, b2h, b2l,
        nullptr, nullptr, nullptr, nullptr, nullptr, nullptr, nullptr, 0);
    mfma_gemm<8, 8, 0, 2, 0><<<dim3(256, 1), 256, 0, stream>>>(
        b2h, b2l, nullptr, nullptr, W34h, W34l, b34, nullptr, nullptr,
        ei, batchv, yv, Wp2, bp2, sel, seg, co);
  }

  // ---- segment softmax + argmax ----
  segmax_sel<<<112, 256, 0, stream>>>(sel, seg, mx_enc);
  exden_kernel<<<112, 256, 0, stream>>>(sel, seg, mx_enc, denom, out);
  probpmax_kernel<<<112, 256, 0, stream>>>(seg, denom, out, pmax_enc);
  argmin_kernel<<<112, 256, 0, stream>>>(seg, out, pmax_enc, amin);
  finalize_kernel<<<1, 64, 0, stream>>>(pmax_enc, amin, out);
}